// Round 12
// baseline (197.910 us; speedup 1.0000x reference)
//
#include <hip/hip_runtime.h>
#include <hip/hip_bf16.h>
#include <math.h>

#define NEG_SLOPE 0.2f
// wave-internal LDS ordering: each wave owns a private LDS slice, so a plain
// lgkmcnt drain orders its own ds ops; no __syncthreads (degrees diverge).
#define LDS_FENCE() asm volatile("s_waitcnt lgkmcnt(0)" ::: "memory")

// ===================== partition-segment CSR build (dst-indexed) =====================
#define CSR_NB 128
#define CSR_CAP 2048
#define XC_NB 128           // x -> bf16 convert blocks (grid-stride)
#define W1T_NB 32           // W1 transpose-convert blocks (128x256 -> 32x32 tiles)
#define WT_NB 64            // W2 transpose-convert blocks (256x256 -> 32x32 tiles)

// fp32 -> bf16 with round-to-nearest-even (finite inputs)
__device__ __forceinline__ ushort f2bf(float f) {
    uint x = __float_as_uint(f);
    x += 0x7fffu + ((x >> 16) & 1u);
    return (ushort)(x >> 16);
}
__device__ __forceinline__ float bf2f(ushort u) {
    return __uint_as_float((uint)u << 16);
}

typedef __attribute__((ext_vector_type(8))) short bf16x8v;   // MFMA A/B fragment (4 VGPRs)
typedef __attribute__((ext_vector_type(4))) float f32x4;     // MFMA C/D fragment

// ---------- prep fat kernel: CSR scatter U x->bf16 U W1^T->bf16 U W2^T->bf16 ----------
__global__ __launch_bounds__(256) void k_prep(
    const int* __restrict__ ei, int E, int N, int NP, int CE,
    int* __restrict__ gcount, int* __restrict__ tmp,
    const float* __restrict__ x, ushort* __restrict__ Xb,
    const float* __restrict__ W1, ushort* __restrict__ W1t,
    const float* __restrict__ W2, ushort* __restrict__ Wt) {
    __shared__ float smem[32 * 33];    // 4.2KB: transpose tile / hist alias
    int t = threadIdx.x;
    if (blockIdx.x < CSR_NB) {
        int* lhist = (int*)smem;
        int b = blockIdx.x;
        for (int p = t; p < 384; p += 256) lhist[p] = 0;
        __syncthreads();
        int Etot = E + N;
        int e0 = b * CE, e1 = min(Etot, e0 + CE);
        for (int e = e0 + t; e < e1; e += 256) {
            int d = (e < E) ? ei[E + e] : (e - E);
            atomicAdd(&lhist[d >> 5], 1);
        }
        __syncthreads();
        for (int p = t; p < NP; p += 256) {
            int c = lhist[p];
            lhist[p] = c ? atomicAdd(&gcount[p], c) : 0;   // reserve range; reuse as cursor
        }
        __syncthreads();
        for (int e = e0 + t; e < e1; e += 256) {
            int s, d;
            if (e < E) { s = ei[e]; d = ei[E + e]; } else { s = d = e - E; }
            int p = d >> 5;
            int pos = atomicAdd(&lhist[p], 1);             // LDS atomic: fast
            tmp[p * CSR_CAP + min(pos, CSR_CAP - 1)] = (s << 5) | (d & 31);
        }
    } else if (blockIdx.x < CSR_NB + XC_NB) {
        // x [N,128] fp32 -> Xb bf16, grid-stride float4 granularity
        int b = blockIdx.x - CSR_NB;
        int nfl4 = N * 32;
        int stride = XC_NB * 256;
        for (int i = b * 256 + t; i < nfl4; i += stride) {
            float4 v = ((const float4*)x)[i];
            ushort4 u;
            u.x = f2bf(v.x); u.y = f2bf(v.y); u.z = f2bf(v.z); u.w = f2bf(v.w);
            ((ushort4*)Xb)[i] = u;
        }
    } else if (blockIdx.x < CSR_NB + XC_NB + W1T_NB) {
        // W1[128 k][256 j] fp32 -> W1t[256 j][128 k] bf16, 32x32 tiles (4 k x 8 j)
        float (*tile)[33] = (float (*)[33])smem;
        int tb = blockIdx.x - CSR_NB - XC_NB;
        int k0 = (tb >> 3) * 32, j0 = (tb & 7) * 32;
        int c = t & 31, i0 = t >> 5;
#pragma unroll
        for (int p = 0; p < 4; ++p) {
            int i = i0 + p * 8;
            tile[i][c] = W1[(size_t)(k0 + i) * 256 + j0 + c];
        }
        __syncthreads();
#pragma unroll
        for (int p = 0; p < 4; ++p) {
            int i = i0 + p * 8;
            W1t[(size_t)(j0 + i) * 128 + k0 + c] = f2bf(tile[c][i]);
        }
    } else {
        // W2[256 k][256 j] fp32 -> Wt[256 j][256 k] bf16, 32x32 tiles (8 k x 8 j)
        float (*tile)[33] = (float (*)[33])smem;
        int tb = blockIdx.x - CSR_NB - XC_NB - W1T_NB;
        int k0 = (tb >> 3) * 32, j0 = (tb & 7) * 32;
        int c = t & 31, i0 = t >> 5;
#pragma unroll
        for (int p = 0; p < 4; ++p) {
            int i = i0 + p * 8;
            tile[i][c] = W2[(size_t)(k0 + i) * 256 + j0 + c];
        }
        __syncthreads();
#pragma unroll
        for (int p = 0; p < 4; ++p) {
            int i = i0 + p * 8;
            Wt[(size_t)(j0 + i) * 256 + k0 + c] = f2bf(tile[c][i]);
        }
    }
}

// ---------- gemm1 via MFMA: Cb[n,0:256] = bf16(Xb[n,:128] @ W1), per-head logits ----
__device__ __forceinline__ void gemm1_mfma_body(int bx,
    const ushort* __restrict__ Xb, const ushort* __restrict__ W1t,
    ushort* __restrict__ Cb, const float* __restrict__ as1,
    const float* __restrict__ ad1, float* __restrict__ als,
    float* __restrict__ ald, int N) {
    int t = threadIdx.x, lane = t & 63, w = t >> 6;
    int n0 = bx * 16;
    int l15 = lane & 15, kb = lane >> 4;
    int col0 = w * 64;
    int arow = min(n0 + l15, N - 1);
    const ushort* Xp = Xb + (size_t)arow * 128 + kb * 8;
    f32x4 acc[4] = {f32x4{0,0,0,0}, f32x4{0,0,0,0}, f32x4{0,0,0,0}, f32x4{0,0,0,0}};
#pragma unroll
    for (int ks = 0; ks < 4; ++ks) {
        bf16x8v a = *(const bf16x8v*)(Xp + ks * 32);
#pragma unroll
        for (int tt = 0; tt < 4; ++tt) {
            const ushort* Bp = W1t + (size_t)(col0 + tt * 16 + l15) * 128 + ks * 32 + kb * 8;
            bf16x8v b = *(const bf16x8v*)Bp;
            acc[tt] = __builtin_amdgcn_mfma_f32_16x16x32_bf16(a, b, acc[tt], 0, 0, 0);
        }
    }
#pragma unroll
    for (int r = 0; r < 4; ++r) {
        int n = n0 + kb * 4 + r;
#pragma unroll
        for (int tt = 0; tt < 4; ++tt) {
            int col = col0 + tt * 16 + l15;
            float v = acc[tt][r];
            float s = v * as1[col];
            float d = v * ad1[col];
            s += __shfl_xor(s, 1); s += __shfl_xor(s, 2);
            s += __shfl_xor(s, 4); s += __shfl_xor(s, 8);
            d += __shfl_xor(d, 1); d += __shfl_xor(d, 2);
            d += __shfl_xor(d, 4); d += __shfl_xor(d, 8);
            if (n < N) {
                Cb[(size_t)n * 256 + col] = f2bf(v);
                if (l15 == 0) {
                    als[n * 16 + (col >> 4)] = s;
                    ald[n * 16 + (col >> 4)] = d;
                }
            }
        }
    }
}

// ---------- union kernel: CSR finalize (NP blocks) + gemm1 MFMA (rows16 blocks) ----
__global__ __launch_bounds__(256) void k_g1f(
    const int* __restrict__ tmp, const int* __restrict__ gcount,
    int2* __restrict__ rowse, int* __restrict__ col, int NP,
    const ushort* __restrict__ Xb, const ushort* __restrict__ W1t,
    ushort* __restrict__ Cb, const float* __restrict__ as1,
    const float* __restrict__ ad1, float* __restrict__ als1,
    float* __restrict__ ald1, int N) {
    if ((int)blockIdx.x >= NP) {
        gemm1_mfma_body(blockIdx.x - NP, Xb, W1t, Cb, as1, ad1, als1, ald1, N);
        return;
    }
    __shared__ int dcnt[32], dcur[32];
    int t = threadIdx.x, p = blockIdx.x;
    int base = p * CSR_CAP;
    int cnt = min(gcount[p], CSR_CAP);
    if (t < 32) dcnt[t] = 0;
    __syncthreads();
    for (int i = t; i < cnt; i += 256) atomicAdd(&dcnt[tmp[base + i] & 31], 1);
    __syncthreads();
    if (t < 32) {
        int v = dcnt[t];
        int x = v;
#pragma unroll
        for (int off = 1; off < 32; off <<= 1) {
            int u = __shfl_up(x, off);
            if (t >= off) x += u;
        }
        int excl = x - v;
        dcur[t] = excl;
        int dst = (p << 5) + t;
        if (dst < N) rowse[dst] = make_int2(base + excl, base + excl + v);
    }
    __syncthreads();
    for (int i = t; i < cnt; i += 256) {
        int v = tmp[base + i];
        int pos = atomicAdd(&dcur[v & 31], 1);
        col[base + pos] = v >> 5;
    }
}

// ---------- gemm2 via MFMA: Cb[n,0:256] = bf16(Xb[n,:] @ W2), fused logit epilogue ----
__global__ __launch_bounds__(256) void k_gemm2_mfma(
    const ushort* __restrict__ Xb, const ushort* __restrict__ Wt,
    ushort* __restrict__ Cb, const float* __restrict__ as2,
    const float* __restrict__ ad2, float* __restrict__ als,
    float* __restrict__ ald, int N) {
    __shared__ float red[4][16][2];
    int t = threadIdx.x, lane = t & 63, w = t >> 6;
    int n0 = blockIdx.x * 16;
    int l15 = lane & 15, kb = lane >> 4;
    int col0 = w * 64;
    int arow = min(n0 + l15, N - 1);
    const ushort* Xp = Xb + (size_t)arow * 256 + kb * 8;
    f32x4 acc[4] = {f32x4{0,0,0,0}, f32x4{0,0,0,0}, f32x4{0,0,0,0}, f32x4{0,0,0,0}};
#pragma unroll
    for (int ks = 0; ks < 8; ++ks) {
        bf16x8v a = *(const bf16x8v*)(Xp + ks * 32);
#pragma unroll
        for (int tt = 0; tt < 4; ++tt) {
            const ushort* Bp = Wt + (size_t)(col0 + tt * 16 + l15) * 256 + ks * 32 + kb * 8;
            bf16x8v b = *(const bf16x8v*)Bp;
            acc[tt] = __builtin_amdgcn_mfma_f32_16x16x32_bf16(a, b, acc[tt], 0, 0, 0);
        }
    }
    // store D (bf16) + logit partials
#pragma unroll
    for (int r = 0; r < 4; ++r) {
        int n = n0 + kb * 4 + r;
        float s = 0.f, d = 0.f;
#pragma unroll
        for (int tt = 0; tt < 4; ++tt) {
            int col = col0 + tt * 16 + l15;
            float v = acc[tt][r];
            if (n < N) Cb[(size_t)n * 256 + col] = f2bf(v);
            s += v * as2[col];
            d += v * ad2[col];
        }
        s += __shfl_xor(s, 1); s += __shfl_xor(s, 2);
        s += __shfl_xor(s, 4); s += __shfl_xor(s, 8);
        d += __shfl_xor(d, 1); d += __shfl_xor(d, 2);
        d += __shfl_xor(d, 4); d += __shfl_xor(d, 8);
        if (l15 == 0) { red[w][kb * 4 + r][0] = s; red[w][kb * 4 + r][1] = d; }
    }
    __syncthreads();
    if (t < 16) {
        int n = n0 + t;
        if (n < N) {
            als[n] = red[0][t][0] + red[1][t][0] + red[2][t][0] + red[3][t][0];
            ald[n] = red[0][t][1] + red[1][t][1] + red[2][t][1] + red[3][t][1];
        }
    }
}

// ---------- fused GAT gather, 1 head, column-half split by BLOCK PARITY ----------
// half = blockIdx.x & 1. Block dispatch round-robins XCDs (XCD ~ bid % 8), so
// half-0 blocks land on even XCDs, half-1 on odd -> each XCD's H working set is
// one 256B-per-row half = 2.56 MB < 4 MB per-XCD L2 -> gather becomes L2-resident
// (full-row version: 5.12 MB > L2, thrashing to L3/HBM). Weight pass (als+expf)
// is duplicated per half -- trivial VALU. Accumulation order per column unchanged.
__global__ __launch_bounds__(256) void k_gather_h1(
    const int2* __restrict__ rowse, const int* __restrict__ col,
    const ushort* __restrict__ Hb, const float* __restrict__ als,
    const float* __restrict__ ald, const float* __restrict__ bias,
    ushort* __restrict__ outb, int N) {
    int bid = blockIdx.x;
    int hf = bid & 1;                  // column half -> XCD parity
    int wave = threadIdx.x >> 6, lane = threadIdx.x & 63;
    int n = (bid >> 1) * 4 + wave;
    if (n >= N) return;
    int2 se2 = rowse[n];
    int start = se2.x, end = se2.y;
    float aldv = ald[n];
    float2 acc = {0.f, 0.f};
    float swsum = 0.f;
    const ushort* Hl = Hb + (hf << 7) + lane * 2;
    for (int base = start; base < end; base += 64) {
        int len = min(64, end - base);
        int s_r = 0;
        float w_r = 0.f;
        if (lane < len) {
            s_r = col[base + lane];
            float v = als[s_r] + aldv;
            v = v >= 0.f ? v : NEG_SLOPE * v;
            w_r = __expf(v);
        }
        swsum += w_r;
        int len8 = (len + 7) & ~7;
        for (int e = 0; e < len8; e += 8) {
            const ushort* hp[8];
            float we[8];
#pragma unroll
            for (int j = 0; j < 8; ++j) {
                hp[j] = Hl + (size_t)__shfl(s_r, e + j) * 256;
                we[j] = __shfl(w_r, e + j);
            }
            ushort2 uv[8];
#pragma unroll
            for (int j = 0; j < 8; ++j) uv[j] = *(const ushort2*)hp[j];
#pragma unroll
            for (int j = 0; j < 8; ++j) {
                acc.x = fmaf(we[j], bf2f(uv[j].x), acc.x);
                acc.y = fmaf(we[j], bf2f(uv[j].y), acc.y);
            }
        }
    }
#pragma unroll
    for (int off = 32; off >= 1; off >>= 1) swsum += __shfl_xor(swsum, off);
    float inv = 1.0f / swsum;
    float2 bv = *(const float2*)(bias + (hf << 7) + lane * 2);
    ushort2 o;
    o.x = f2bf(fmaf(acc.x, inv, bv.x));
    o.y = f2bf(fmaf(acc.y, inv, bv.y));
    *(ushort2*)(outb + (size_t)n * 256 + (hf << 7) + lane * 2) = o;
}

// ---------- fused GAT gather, 16 heads x 16ch, column-half split by BLOCK PARITY ----
// 8 heads per half; lane computes weights for (edge-slot lane>>3, head lane&7);
// w_lds write k*64+lane = linear (conflict-free); read 8-way broadcast groups.
__global__ __launch_bounds__(256) void k_gather_h16(
    const int2* __restrict__ rowse, const int* __restrict__ col,
    const ushort* __restrict__ Hb, const float* __restrict__ als,
    const float* __restrict__ ald, const float* __restrict__ bias,
    ushort* __restrict__ outb, int N) {
    __shared__ float w_lds[4][64 * 8];
    int bid = blockIdx.x;
    int hf = bid & 1;                  // column half -> XCD parity
    int wave = threadIdx.x >> 6, lane = threadIdx.x & 63;
    int n = (bid >> 1) * 4 + wave;
    if (n >= N) return;
    int2 se2 = rowse[n];
    int start = se2.x, end = se2.y;
    int hq = (hf << 3) + (lane & 7);   // global head this lane computes logits for
    int eW = lane >> 3;                // edge sub-slot 0..7
    float aldW = ald[n * 16 + hq];
    float2 acc = {0.f, 0.f};
    float swp = 0.f;                   // partial w-sum for head hq
    const ushort* Hl = Hb + (hf << 7) + lane * 2;
    for (int base = start; base < end; base += 64) {
        int len = min(64, end - base);
        int s_r = (lane < len) ? col[base + lane] : 0;
#pragma unroll
        for (int k = 0; k < 8; ++k) {
            int esub = (k << 3) + eW;
            int s = __shfl(s_r, esub);
            float w = 0.f;
            if (esub < len) {
                float v = als[s * 16 + hq] + aldW;
                v = v >= 0.f ? v : NEG_SLOPE * v;
                w = __expf(v);
            }
            w_lds[wave][(esub << 3) + (lane & 7)] = w;   // = k*64+lane: linear
            swp += w;
        }
        LDS_FENCE();
        int len8 = (len + 7) & ~7;
        for (int e = 0; e < len8; e += 8) {
            const ushort* hp[8];
            float we[8];
#pragma unroll
            for (int j = 0; j < 8; ++j) {
                hp[j] = Hl + (size_t)__shfl(s_r, e + j) * 256;
                we[j] = w_lds[wave][((e + j) << 3) + (lane >> 3)];
            }
            ushort2 uv[8];
#pragma unroll
            for (int j = 0; j < 8; ++j) uv[j] = *(const ushort2*)hp[j];
#pragma unroll
            for (int j = 0; j < 8; ++j) {
                acc.x = fmaf(we[j], bf2f(uv[j].x), acc.x);
                acc.y = fmaf(we[j], bf2f(uv[j].y), acc.y);
            }
        }
        LDS_FENCE();   // WAR guard: next chunk's weight phase overwrites w_lds
    }
    // head totals live on lanes sharing lane&7
    swp += __shfl_xor(swp, 8);
    swp += __shfl_xor(swp, 16);
    swp += __shfl_xor(swp, 32);
    float inv = 1.0f / __shfl(swp, lane >> 3);   // head of this lane's col pair
    float2 bv = *(const float2*)(bias + (hf << 7) + lane * 2);
    ushort2 o;
    o.x = f2bf(fmaxf(fmaf(acc.x, inv, bv.x), 0.f));
    o.y = f2bf(fmaxf(fmaf(acc.y, inv, bv.y), 0.f));
    *(ushort2*)(outb + (size_t)n * 256 + (hf << 7) + lane * 2) = o;
}

// ---------- fused mean-pool + final linear: one block per graph (B is bf16) ----------
__device__ __forceinline__ int lower_bound_i(const int* __restrict__ a, int n, int v) {
    int lo = 0, hi = n;
    while (lo < hi) {
        int mid = (lo + hi) >> 1;
        if (a[mid] < v) lo = mid + 1; else hi = mid;
    }
    return lo;
}

__global__ __launch_bounds__(1024) void k_pool_final(const ushort* __restrict__ Bb,
                                                     const int* __restrict__ batch,
                                                     const float* __restrict__ lw,
                                                     const float* __restrict__ lb,
                                                     float* __restrict__ out,
                                                     int N, int L) {
    __shared__ float psum[4][256];
    __shared__ float csum[256];
    int t = threadIdx.x;
    int c = t & 255, q = t >> 8;
    int g = blockIdx.x;
    int lo = lower_bound_i(batch, N, g);
    int hi = lower_bound_i(batch, N, g + 1);
    int len = hi - lo;
    int per = (len + 3) >> 2;
    int s0 = lo + q * per, s1 = min(hi, s0 + per);
    float acc = 0.f;
    for (int r = s0; r < s1; ++r) acc += bf2f(Bb[(size_t)r * 256 + c]);
    psum[q][c] = acc;
    __syncthreads();
    if (t < 256) csum[t] = psum[0][t] + psum[1][t] + psum[2][t] + psum[3][t];
    __syncthreads();
    int wave = t >> 6, lane = t & 63;
    if (wave < L) {
        int l = wave;
        float a = csum[lane] * lw[lane * L + l] +
                  csum[lane + 64] * lw[(lane + 64) * L + l] +
                  csum[lane + 128] * lw[(lane + 128) * L + l] +
                  csum[lane + 192] * lw[(lane + 192) * L + l];
#pragma unroll
        for (int off = 32; off >= 1; off >>= 1) a += __shfl_xor(a, off);
        if (lane == 0) out[g * L + l] = a / fmaxf((float)len, 1.0f) + lb[l];
    }
}

extern "C" void kernel_launch(void* const* d_in, const int* in_sizes, int n_in,
                              void* d_out, int out_size, void* d_ws, size_t ws_size,
                              hipStream_t stream) {
    const float* x   = (const float*)d_in[0];
    const int*   ei  = (const int*)d_in[1];
    const int*   bat = (const int*)d_in[2];
    const float* W1  = (const float*)d_in[3];
    const float* as1 = (const float*)d_in[4];
    const float* ad1 = (const float*)d_in[5];
    const float* b1  = (const float*)d_in[6];
    const float* W2  = (const float*)d_in[7];
    const float* as2 = (const float*)d_in[8];
    const float* ad2 = (const float*)d_in[9];
    const float* b2  = (const float*)d_in[10];
    const float* lw  = (const float*)d_in[11];
    const float* lb  = (const float*)d_in[12];
    float* out = (float*)d_out;

    const int N = in_sizes[2];        // 10000
    const int E = in_sizes[1] / 2;    // 320000
    const int G = 64, L = 10;
    const int Etot = E + N;
    const int NP = (N + 31) >> 5;     // partitions of 32 dsts (313)
    const int CE = (Etot + CSR_NB - 1) / CSR_NB;

    // workspace layout (A/B keep fp32-sized slots; used as bf16)
    float* A    = (float*)d_ws;              // [N,256] bf16 h1 then h2 (as ushort)
    float* B    = A + (size_t)N * 256;       // [N,256] bf16 out1 then out2 (as ushort)
    float* als1 = B + (size_t)N * 256;       // [N,16]
    float* ald1 = als1 + (size_t)N * 16;
    float* als2 = ald1 + (size_t)N * 16;     // [N]
    float* ald2 = als2 + N;
    int2* rowse = (int2*)(ald2 + N);         // [N] {start,end}
    int* col    = (int*)(rowse + N);         // [NP*CAP] strided segments
    int* tmp    = col + (size_t)NP * CSR_CAP;// [NP*CAP] packed (src<<5)|d5
    int* gcount = tmp + (size_t)NP * CSR_CAP;// [NP]
    // 64B-align the bf16 region so all 16B vector loads/stores are natural
    ushort* Wt  = (ushort*)(((uintptr_t)(gcount + NP) + 63) & ~(uintptr_t)63);
    ushort* W1t = Wt + 256 * 256;            // [256][128] bf16 W1 transposed
    ushort* Xb  = W1t + 256 * 128;           // [N][128] bf16 x
    ushort* Abf = (ushort*)A;
    ushort* Bbf = (ushort*)B;

    const int BS = 256;
    auto nb = [](int n, int b) { return (n + b - 1) / b; };
    int nodes4 = nb(N, 4);
    int rows16 = nb(N, 16);

    // ---- zero partition counters; prep fat kernel (scatter U converts) ----
    hipMemsetAsync(gcount, 0, NP * sizeof(int), stream);
    k_prep<<<CSR_NB + XC_NB + W1T_NB + WT_NB, BS, 0, stream>>>(
        ei, E, N, NP, CE, gcount, tmp, x, Xb, W1, W1t, W2, Wt);

    // ---- CSR finalize U gemm1 (MFMA) ----
    k_g1f<<<NP + rows16, BS, 0, stream>>>(tmp, gcount, rowse, col, NP,
                                          Xb, W1t, Abf, as1, ad1, als1, ald1, N);

    // ---- layer 1 aggregate (half-split, XCD-parity partitioned) ----
    k_gather_h16<<<nodes4 * 2, BS, 0, stream>>>(rowse, col, Abf, als1, ald1, b1, Bbf, N);

    // ---- layer 2 (MFMA) ----
    k_gemm2_mfma<<<rows16, BS, 0, stream>>>(Bbf, Wt, Abf, as2, ad2, als2, ald2, N);
    k_gather_h1<<<nodes4 * 2, BS, 0, stream>>>(rowse, col, Abf, als2, ald2, b2, Bbf, N);

    // ---- fused pool + final linear ----
    k_pool_final<<<G, 1024, 0, stream>>>(Bbf, bat, lw, lb, out, N, L);
}

// Round 13
// 193.042 us; speedup vs baseline: 1.0252x; 1.0252x over previous
//
#include <hip/hip_runtime.h>
#include <hip/hip_bf16.h>
#include <math.h>

#define NEG_SLOPE 0.2f
// wave-internal LDS ordering: each wave owns a private LDS slice, so a plain
// lgkmcnt drain orders its own ds ops; no __syncthreads (degrees diverge).
#define LDS_FENCE() asm volatile("s_waitcnt lgkmcnt(0)" ::: "memory")

// ===================== partition-segment CSR build (dst-indexed) =====================
#define CSR_NB 128
#define CSR_CAP 2048
#define WT_NB 64            // W2 transpose-convert blocks riding in the fat kernel

// fp32 -> bf16 with round-to-nearest-even (finite inputs)
__device__ __forceinline__ ushort f2bf(float f) {
    uint x = __float_as_uint(f);
    x += 0x7fffu + ((x >> 16) & 1u);
    return (ushort)(x >> 16);
}
__device__ __forceinline__ float bf2f(ushort u) {
    return __uint_as_float((uint)u << 16);
}

typedef __attribute__((ext_vector_type(8))) short bf16x8v;   // MFMA A/B fragment (4 VGPRs)
typedef __attribute__((ext_vector_type(4))) float f32x4;     // MFMA C/D fragment

// ---------- gemm1 via MFMA, ZERO staging buffers: A from fp32 x (in-reg convert),
// B from W1 directly (8 strided fp32 loads per fragment; W1=128KB, L2-resident).
// Block = 16 rows x 256 cols, 4 waves; wave w owns cols [w*64, w*64+64).
// A: lane holds x[n0+(lane&15)][ks*32+(lane>>4)*8+j] (32B fp32 -> bf16x8);
// B: W1[ks*32+(lane>>4)*8+j][col] -- same values/rounding as round-11's W1t path.
// D: row=(lane>>4)*4+r, col=lane&15 [verified rounds 9/11]. Head=col>>4 lives in
// one 16-lane group -> logits reduce with 4 shfl_xor, no LDS.
__device__ __forceinline__ void gemm1_mfma_body(int bx,
    const float* __restrict__ x, const float* __restrict__ W1,
    ushort* __restrict__ Cb, const float* __restrict__ as1,
    const float* __restrict__ ad1, float* __restrict__ als,
    float* __restrict__ ald, int N) {
    int t = threadIdx.x, lane = t & 63, w = t >> 6;
    int n0 = bx * 16;
    int l15 = lane & 15, kb = lane >> 4;
    int col0 = w * 64;
    int arow = min(n0 + l15, N - 1);
    const float* Xp = x + (size_t)arow * 128 + kb * 8;
    f32x4 acc[4] = {f32x4{0,0,0,0}, f32x4{0,0,0,0}, f32x4{0,0,0,0}, f32x4{0,0,0,0}};
#pragma unroll
    for (int ks = 0; ks < 4; ++ks) {
        float4 xa = *(const float4*)(Xp + ks * 32);
        float4 xc = *(const float4*)(Xp + ks * 32 + 4);
        bf16x8v a;
        a[0] = (short)f2bf(xa.x); a[1] = (short)f2bf(xa.y);
        a[2] = (short)f2bf(xa.z); a[3] = (short)f2bf(xa.w);
        a[4] = (short)f2bf(xc.x); a[5] = (short)f2bf(xc.y);
        a[6] = (short)f2bf(xc.z); a[7] = (short)f2bf(xc.w);
#pragma unroll
        for (int tt = 0; tt < 4; ++tt) {
            int col = col0 + tt * 16 + l15;
            const float* Wp = W1 + (size_t)(ks * 32 + kb * 8) * 256 + col;
            bf16x8v b;
#pragma unroll
            for (int j = 0; j < 8; ++j) b[j] = (short)f2bf(Wp[(size_t)j * 256]);
            acc[tt] = __builtin_amdgcn_mfma_f32_16x16x32_bf16(a, b, acc[tt], 0, 0, 0);
        }
    }
#pragma unroll
    for (int r = 0; r < 4; ++r) {
        int n = n0 + kb * 4 + r;
#pragma unroll
        for (int tt = 0; tt < 4; ++tt) {
            int col = col0 + tt * 16 + l15;
            float v = acc[tt][r];
            float s = v * as1[col];
            float d = v * ad1[col];
            s += __shfl_xor(s, 1); s += __shfl_xor(s, 2);
            s += __shfl_xor(s, 4); s += __shfl_xor(s, 8);
            d += __shfl_xor(d, 1); d += __shfl_xor(d, 2);
            d += __shfl_xor(d, 4); d += __shfl_xor(d, 8);
            if (n < N) {
                Cb[(size_t)n * 256 + col] = f2bf(v);
                if (l15 == 0) {
                    als[n * 16 + (col >> 4)] = s;
                    ald[n * 16 + (col >> 4)] = d;
                }
            }
        }
    }
}

// ---------- fat kernel: CSR scatter UNION W2-transpose-convert UNION gemm1-MFMA ----
// All three groups independent: scatter feeds k_csr_final (next dispatch); Wt feeds
// k_gemm2_mfma (later dispatch); gemm1 reads only inputs.
__global__ __launch_bounds__(256) void k_scatter_gemm1(
    const int* __restrict__ ei, int E, int N, int NP, int CE,
    int* __restrict__ gcount, int* __restrict__ tmp,
    const float* __restrict__ x, const float* __restrict__ W1, ushort* __restrict__ A,
    const float* __restrict__ as1, const float* __restrict__ ad1,
    float* __restrict__ als1, float* __restrict__ ald1,
    const float* __restrict__ W2, ushort* __restrict__ Wt) {
    __shared__ float smem[32 * 33];    // 4.2KB: hist alias / transpose tile
    int t = threadIdx.x;
    if (blockIdx.x < CSR_NB) {
        int* lhist = (int*)smem;
        int b = blockIdx.x;
        for (int p = t; p < 384; p += 256) lhist[p] = 0;
        __syncthreads();
        int Etot = E + N;
        int e0 = b * CE, e1 = min(Etot, e0 + CE);
        for (int e = e0 + t; e < e1; e += 256) {
            int d = (e < E) ? ei[E + e] : (e - E);
            atomicAdd(&lhist[d >> 5], 1);
        }
        __syncthreads();
        for (int p = t; p < NP; p += 256) {
            int c = lhist[p];
            lhist[p] = c ? atomicAdd(&gcount[p], c) : 0;   // reserve range; reuse as cursor
        }
        __syncthreads();
        for (int e = e0 + t; e < e1; e += 256) {
            int s, d;
            if (e < E) { s = ei[e]; d = ei[E + e]; } else { s = d = e - E; }
            int p = d >> 5;
            int pos = atomicAdd(&lhist[p], 1);             // LDS atomic: fast
            tmp[p * CSR_CAP + min(pos, CSR_CAP - 1)] = (s << 5) | (d & 31);
        }
    } else if (blockIdx.x < CSR_NB + WT_NB) {
        // W2[256 k][256 j] fp32 -> Wt[256 j][256 k] bf16, 32x32 tiles
        float (*tile)[33] = (float (*)[33])smem;
        int tb = blockIdx.x - CSR_NB;
        int k0 = (tb >> 3) * 32, j0 = (tb & 7) * 32;
        int c = t & 31, i0 = t >> 5;
#pragma unroll
        for (int p = 0; p < 4; ++p) {
            int i = i0 + p * 8;
            tile[i][c] = W2[(size_t)(k0 + i) * 256 + j0 + c];
        }
        __syncthreads();
#pragma unroll
        for (int p = 0; p < 4; ++p) {
            int i = i0 + p * 8;
            Wt[(size_t)(j0 + i) * 256 + k0 + c] = f2bf(tile[c][i]);
        }
    } else {
        gemm1_mfma_body(blockIdx.x - CSR_NB - WT_NB, x, W1, A, as1, ad1, als1, ald1, N);
    }
}

// ---------- CSR finalize: one block per partition -> rowse {start,end} + col ----------
__global__ __launch_bounds__(256) void k_csr_final(const int* __restrict__ tmp,
                                                   const int* __restrict__ gcount,
                                                   int2* __restrict__ rowse,
                                                   int* __restrict__ col, int N) {
    __shared__ int dcnt[32], dcur[32];
    int t = threadIdx.x, p = blockIdx.x;
    int base = p * CSR_CAP;
    int cnt = min(gcount[p], CSR_CAP);
    if (t < 32) dcnt[t] = 0;
    __syncthreads();
    for (int i = t; i < cnt; i += 256) atomicAdd(&dcnt[tmp[base + i] & 31], 1);
    __syncthreads();
    if (t < 32) {
        int v = dcnt[t];
        int x = v;
#pragma unroll
        for (int off = 1; off < 32; off <<= 1) {
            int u = __shfl_up(x, off);
            if (t >= off) x += u;
        }
        int excl = x - v;
        dcur[t] = excl;
        int dst = (p << 5) + t;
        if (dst < N) rowse[dst] = make_int2(base + excl, base + excl + v);
    }
    __syncthreads();
    for (int i = t; i < cnt; i += 256) {
        int v = tmp[base + i];
        int pos = atomicAdd(&dcur[v & 31], 1);
        col[base + pos] = v >> 5;
    }
}

// ---------- gemm2 via MFMA: Cb[n,0:256] = bf16(Xb[n,:] @ W2), fused logit epilogue ----
__global__ __launch_bounds__(256) void k_gemm2_mfma(
    const ushort* __restrict__ Xb, const ushort* __restrict__ Wt,
    ushort* __restrict__ Cb, const float* __restrict__ as2,
    const float* __restrict__ ad2, float* __restrict__ als,
    float* __restrict__ ald, int N) {
    __shared__ float red[4][16][2];
    int t = threadIdx.x, lane = t & 63, w = t >> 6;
    int n0 = blockIdx.x * 16;
    int l15 = lane & 15, kb = lane >> 4;
    int col0 = w * 64;
    int arow = min(n0 + l15, N - 1);
    const ushort* Xp = Xb + (size_t)arow * 256 + kb * 8;
    f32x4 acc[4] = {f32x4{0,0,0,0}, f32x4{0,0,0,0}, f32x4{0,0,0,0}, f32x4{0,0,0,0}};
#pragma unroll
    for (int ks = 0; ks < 8; ++ks) {
        bf16x8v a = *(const bf16x8v*)(Xp + ks * 32);
#pragma unroll
        for (int tt = 0; tt < 4; ++tt) {
            const ushort* Bp = Wt + (size_t)(col0 + tt * 16 + l15) * 256 + ks * 32 + kb * 8;
            bf16x8v b = *(const bf16x8v*)Bp;
            acc[tt] = __builtin_amdgcn_mfma_f32_16x16x32_bf16(a, b, acc[tt], 0, 0, 0);
        }
    }
    // store D (bf16) + logit partials
#pragma unroll
    for (int r = 0; r < 4; ++r) {
        int n = n0 + kb * 4 + r;
        float s = 0.f, d = 0.f;
#pragma unroll
        for (int tt = 0; tt < 4; ++tt) {
            int col = col0 + tt * 16 + l15;
            float v = acc[tt][r];
            if (n < N) Cb[(size_t)n * 256 + col] = f2bf(v);
            s += v * as2[col];
            d += v * ad2[col];
        }
        s += __shfl_xor(s, 1); s += __shfl_xor(s, 2);
        s += __shfl_xor(s, 4); s += __shfl_xor(s, 8);
        d += __shfl_xor(d, 1); d += __shfl_xor(d, 2);
        d += __shfl_xor(d, 4); d += __shfl_xor(d, 8);
        if (l15 == 0) { red[w][kb * 4 + r][0] = s; red[w][kb * 4 + r][1] = d; }
    }
    __syncthreads();
    if (t < 16) {
        int n = n0 + t;
        if (n < N) {
            als[n] = red[0][t][0] + red[1][t][0] + red[2][t][0] + red[3][t][0];
            ald[n] = red[0][t][1] + red[1][t][1] + red[2][t][1] + red[3][t][1];
        }
    }
}

// ---------- fused GAT gather, 1 head: one wave per node, bf16 full rows, 8-deep MLP ----
__global__ __launch_bounds__(256) void k_gather_h1(
    const int2* __restrict__ rowse, const int* __restrict__ col,
    const ushort* __restrict__ Hb, const float* __restrict__ als,
    const float* __restrict__ ald, const float* __restrict__ bias,
    ushort* __restrict__ outb, int N) {
    int wave = threadIdx.x >> 6, lane = threadIdx.x & 63;
    int n = blockIdx.x * 4 + wave;
    if (n >= N) return;
    int2 se2 = rowse[n];
    int start = se2.x, end = se2.y;
    float aldv = ald[n];
    float4 acc = {0.f, 0.f, 0.f, 0.f};
    float swsum = 0.f;
    const ushort* Hl = Hb + lane * 4;
    for (int base = start; base < end; base += 64) {
        int len = min(64, end - base);
        int s_r = 0;
        float w_r = 0.f;
        if (lane < len) {
            s_r = col[base + lane];
            float v = als[s_r] + aldv;
            v = v >= 0.f ? v : NEG_SLOPE * v;
            w_r = __expf(v);
        }
        swsum += w_r;
        int len8 = (len + 7) & ~7;
        for (int e = 0; e < len8; e += 8) {
            const ushort* hp[8];
            float we[8];
#pragma unroll
            for (int j = 0; j < 8; ++j) {
                hp[j] = Hl + (size_t)__shfl(s_r, e + j) * 256;
                we[j] = __shfl(w_r, e + j);
            }
            ushort4 uv[8];
#pragma unroll
            for (int j = 0; j < 8; ++j) uv[j] = *(const ushort4*)hp[j];
#pragma unroll
            for (int j = 0; j < 8; ++j) {
                acc.x = fmaf(we[j], bf2f(uv[j].x), acc.x);
                acc.y = fmaf(we[j], bf2f(uv[j].y), acc.y);
                acc.z = fmaf(we[j], bf2f(uv[j].z), acc.z);
                acc.w = fmaf(we[j], bf2f(uv[j].w), acc.w);
            }
        }
    }
#pragma unroll
    for (int off = 32; off >= 1; off >>= 1) swsum += __shfl_xor(swsum, off);
    float inv = 1.0f / swsum;
    float4 bv = *(const float4*)(bias + lane * 4);
    ushort4 o;
    o.x = f2bf(fmaf(acc.x, inv, bv.x));
    o.y = f2bf(fmaf(acc.y, inv, bv.y));
    o.z = f2bf(fmaf(acc.z, inv, bv.z));
    o.w = f2bf(fmaf(acc.w, inv, bv.w));
    *(ushort4*)(outb + (size_t)n * 256 + lane * 4) = o;
}

// ---------- fused GAT gather, 16 heads x 16ch: bf16 full rows, reg-broadcast src ----
__global__ __launch_bounds__(256) void k_gather_h16(
    const int2* __restrict__ rowse, const int* __restrict__ col,
    const ushort* __restrict__ Hb, const float* __restrict__ als,
    const float* __restrict__ ald, const float* __restrict__ bias,
    ushort* __restrict__ outb, int N) {
    __shared__ float w_lds[4][64 * 16];
    int wave = threadIdx.x >> 6, lane = threadIdx.x & 63;
    int n = blockIdx.x * 4 + wave;
    if (n >= N) return;
    int2 se2 = rowse[n];
    int start = se2.x, end = se2.y;
    int hq = lane & 15;                // head this lane computes logits for
    int eq = lane >> 4;                // edge sub-slot 0..3
    float aldW = ald[n * 16 + hq];
    float4 acc = {0.f, 0.f, 0.f, 0.f};
    float swp = 0.f;                   // partial w-sum for head hq
    const ushort* Hl = Hb + lane * 4;
    for (int base = start; base < end; base += 64) {
        int len = min(64, end - base);
        int s_r = (lane < len) ? col[base + lane] : 0;
#pragma unroll
        for (int k = 0; k < 16; ++k) {
            int esub = (k << 2) + eq;
            int s = __shfl(s_r, esub);
            float w = 0.f;
            if (esub < len) {
                float v = als[s * 16 + hq] + aldW;
                v = v >= 0.f ? v : NEG_SLOPE * v;
                w = __expf(v);
            }
            w_lds[wave][(esub << 4) + hq] = w;   // every slot written (0 for pads)
            swp += w;
        }
        LDS_FENCE();
        int len8 = (len + 7) & ~7;
        for (int e = 0; e < len8; e += 8) {
            const ushort* hp[8];
            float we[8];
#pragma unroll
            for (int j = 0; j < 8; ++j) {
                hp[j] = Hl + (size_t)__shfl(s_r, e + j) * 256;
                we[j] = w_lds[wave][((e + j) << 4) + (lane >> 2)];
            }
            ushort4 uv[8];
#pragma unroll
            for (int j = 0; j < 8; ++j) uv[j] = *(const ushort4*)hp[j];
#pragma unroll
            for (int j = 0; j < 8; ++j) {
                acc.x = fmaf(we[j], bf2f(uv[j].x), acc.x);
                acc.y = fmaf(we[j], bf2f(uv[j].y), acc.y);
                acc.z = fmaf(we[j], bf2f(uv[j].z), acc.z);
                acc.w = fmaf(we[j], bf2f(uv[j].w), acc.w);
            }
        }
        LDS_FENCE();   // WAR guard: next chunk's weight phase overwrites w_lds
    }
    // head totals live on lanes sharing (lane&15)
    swp += __shfl_xor(swp, 16);
    swp += __shfl_xor(swp, 32);
    float inv = 1.0f / __shfl(swp, lane >> 2);   // head of this lane's col group
    float4 bv = *(const float4*)(bias + lane * 4);
    ushort4 o;
    o.x = f2bf(fmaxf(fmaf(acc.x, inv, bv.x), 0.f));
    o.y = f2bf(fmaxf(fmaf(acc.y, inv, bv.y), 0.f));
    o.z = f2bf(fmaxf(fmaf(acc.z, inv, bv.z), 0.f));
    o.w = f2bf(fmaxf(fmaf(acc.w, inv, bv.w), 0.f));
    *(ushort4*)(outb + (size_t)n * 256 + lane * 4) = o;
}

// ---------- fused mean-pool + final linear: one block per graph (B is bf16) ----------
__device__ __forceinline__ int lower_bound_i(const int* __restrict__ a, int n, int v) {
    int lo = 0, hi = n;
    while (lo < hi) {
        int mid = (lo + hi) >> 1;
        if (a[mid] < v) lo = mid + 1; else hi = mid;
    }
    return lo;
}

__global__ __launch_bounds__(1024) void k_pool_final(const ushort* __restrict__ Bb,
                                                     const int* __restrict__ batch,
                                                     const float* __restrict__ lw,
                                                     const float* __restrict__ lb,
                                                     float* __restrict__ out,
                                                     int N, int L) {
    __shared__ float psum[4][256];
    __shared__ float csum[256];
    int t = threadIdx.x;
    int c = t & 255, q = t >> 8;
    int g = blockIdx.x;
    int lo = lower_bound_i(batch, N, g);
    int hi = lower_bound_i(batch, N, g + 1);
    int len = hi - lo;
    int per = (len + 3) >> 2;
    int s0 = lo + q * per, s1 = min(hi, s0 + per);
    float acc = 0.f;
    for (int r = s0; r < s1; ++r) acc += bf2f(Bb[(size_t)r * 256 + c]);
    psum[q][c] = acc;
    __syncthreads();
    if (t < 256) csum[t] = psum[0][t] + psum[1][t] + psum[2][t] + psum[3][t];
    __syncthreads();
    int wave = t >> 6, lane = t & 63;
    if (wave < L) {
        int l = wave;
        float a = csum[lane] * lw[lane * L + l] +
                  csum[lane + 64] * lw[(lane + 64) * L + l] +
                  csum[lane + 128] * lw[(lane + 128) * L + l] +
                  csum[lane + 192] * lw[(lane + 192) * L + l];
#pragma unroll
        for (int off = 32; off >= 1; off >>= 1) a += __shfl_xor(a, off);
        if (lane == 0) out[g * L + l] = a / fmaxf((float)len, 1.0f) + lb[l];
    }
}

extern "C" void kernel_launch(void* const* d_in, const int* in_sizes, int n_in,
                              void* d_out, int out_size, void* d_ws, size_t ws_size,
                              hipStream_t stream) {
    const float* x   = (const float*)d_in[0];
    const int*   ei  = (const int*)d_in[1];
    const int*   bat = (const int*)d_in[2];
    const float* W1  = (const float*)d_in[3];
    const float* as1 = (const float*)d_in[4];
    const float* ad1 = (const float*)d_in[5];
    const float* b1  = (const float*)d_in[6];
    const float* W2  = (const float*)d_in[7];
    const float* as2 = (const float*)d_in[8];
    const float* ad2 = (const float*)d_in[9];
    const float* b2  = (const float*)d_in[10];
    const float* lw  = (const float*)d_in[11];
    const float* lb  = (const float*)d_in[12];
    float* out = (float*)d_out;

    const int N = in_sizes[2];        // 10000
    const int E = in_sizes[1] / 2;    // 320000
    const int G = 64, L = 10;
    const int Etot = E + N;
    const int NP = (N + 31) >> 5;     // partitions of 32 dsts (313)
    const int CE = (Etot + CSR_NB - 1) / CSR_NB;

    // workspace layout (A/B keep fp32-sized slots; used as bf16)
    float* A    = (float*)d_ws;              // [N,256] bf16 h1 then h2 (as ushort)
    float* B    = A + (size_t)N * 256;       // [N,256] bf16 out1 then out2 (as ushort)
    float* als1 = B + (size_t)N * 256;       // [N,16]
    float* ald1 = als1 + (size_t)N * 16;
    float* als2 = ald1 + (size_t)N * 16;     // [N]
    float* ald2 = als2 + N;
    int2* rowse = (int2*)(ald2 + N);         // [N] {start,end}
    int* col    = (int*)(rowse + N);         // [NP*CAP] strided segments
    int* tmp    = col + (size_t)NP * CSR_CAP;// [NP*CAP] packed (src<<5)|d5
    int* gcount = tmp + (size_t)NP * CSR_CAP;// [NP]
    // 64B-align the bf16 region so all 16B vector loads/stores are natural
    ushort* Wt  = (ushort*)(((uintptr_t)(gcount + NP) + 63) & ~(uintptr_t)63);
    ushort* Abf = (ushort*)A;
    ushort* Bbf = (ushort*)B;

    const int BS = 256;
    auto nb = [](int n, int b) { return (n + b - 1) / b; };
    int nodes4 = nb(N, 4);
    int rows16 = nb(N, 16);

    // ---- zero partition counters; fat kernel (scatter U W2t-convert U gemm1-MFMA) ----
    hipMemsetAsync(gcount, 0, NP * sizeof(int), stream);
    k_scatter_gemm1<<<CSR_NB + WT_NB + rows16, BS, 0, stream>>>(
        ei, E, N, NP, CE, gcount, tmp, x, W1, Abf, as1, ad1, als1, ald1, W2, Wt);
    k_csr_final<<<NP, BS, 0, stream>>>(tmp, gcount, rowse, col, N);

    // ---- layer 1 aggregate ----
    k_gather_h16<<<nodes4, BS, 0, stream>>>(rowse, col, Abf, als1, ald1, b1, Bbf, N);

    // ---- layer 2 (MFMA) ----
    k_gemm2_mfma<<<rows16, BS, 0, stream>>>(Bbf, Wt, Abf, as2, ad2, als2, ald2, N);
    k_gather_h1<<<nodes4, BS, 0, stream>>>(rowse, col, Abf, als2, ald2, b2, Bbf, N);

    // ---- fused pool + final linear ----
    k_pool_final<<<G, 1024, 0, stream>>>(Bbf, bat, lw, lb, out, N, L);
}